// Round 5
// baseline (178.191 us; speedup 1.0000x reference)
//
#include <hip/hip_runtime.h>

#define TH 8               // output rows per block
#define NIT (TH + 4)       // pipeline iterations (4 warm-up/halo rows)
#define XCOLS 512          // columns per x-block (2 x-blocks cover W=1024)

__global__ __launch_bounds__(256, 8)
void bilateral_fused(const float* __restrict__ bright,
                     const float* __restrict__ dark,
                     const float* __restrict__ depths,
                     const float* __restrict__ p_dv,
                     const float* __restrict__ p_sv,
                     const float* __restrict__ p_de,
                     const float* __restrict__ p_deps,
                     const float* __restrict__ p_ce,
                     float* __restrict__ out,
                     int H, int W)
{
    const float LOG2E = 1.44269504088896340736f;
    const float kd  = -LOG2E / (2.0f * p_dv[0]);   // ~ -1803: weight underflows
    const float ks  = -LOG2E / (2.0f * p_sv[0]);   //   to exact 0 for rel>~0.29
    const float de  = p_de[0];
    const float dke = p_deps[0];
    const float ce  = p_ce[0];
    const float ks1 = ks;
    const float ks4 = 4.0f * ks;
    const float NEG = -1e30f;   // exp2(-1e30 + finite) == 0.0f exactly

    const int t  = threadIdx.x;                    // 0..255
    const int c  = blockIdx.x * XCOLS + 2 * t;     // this thread's cols c, c+1
    const int y0 = blockIdx.y * TH;

    const size_t plane = (size_t)H * W;
    const float* bB = bright + (size_t)blockIdx.z * plane;
    const float* dB = dark   + (size_t)blockIdx.z * plane;
    const float* zB = depths + (size_t)blockIdx.z * plane;
    float*     outB = out    + (size_t)blockIdx.z * plane;

    // clamped side-window columns (8B aligned; only clamps at image edges —
    // interior x-block boundaries read the neighbor's columns through L1/L2)
    const int colL = max(c - 2, 0);
    const int colR = min(c + 2, W - 2);

    // per-thread spatial-exponent constants with column zero-pad folded in:
    // OOB tap -> exponent -1e30 -> weight exactly 0 (matches zero-pad ref)
    const float kA0 = (c - 2 >= 0) ? ks4 : NEG;   // px0 tap col c-2
    const float kA1 = (c - 1 >= 0) ? ks1 : NEG;   // px0 tap col c-1
    const float kA3 = ks1;                        // px0 tap col c+1 (always ok)
    const float kA4 = (c + 2 <  W) ? ks4 : NEG;   // px0 tap col c+2
    const float kB0 = (c - 1 >= 0) ? ks4 : NEG;   // px1 tap col c-1
    const float kB1 = ks1;                        // px1 tap col c   (always ok)
    const float kB3 = (c + 2 <  W) ? ks1 : NEG;   // px1 tap col c+2
    const float kB4 = (c + 3 <  W) ? ks4 : NEG;   // px1 tap col c+3

    auto wexp = [&](float zp, float invz, float kspat) {
        const float u = fmaf(zp, invz, -1.0f);
        return exp2f(fmaf(u * kd, u, kspat));
    };

    // 5-deep register pipeline of horizontally-blurred rows (+ center depths)
    float pb0[5], pb1[5], pd0[5], pd1[5], pz0[5], pz1[5];

#pragma unroll
    for (int i = 0; i < NIT; ++i) {
        const int s  = i % 5;            // static after full unroll
        const int gy = y0 + i - 2;

        if ((unsigned)gy < (unsigned)H) {    // block-uniform branch
            const size_t ro = (size_t)gy * W;
            const float2 bL = *(const float2*)(bB + ro + colL);
            const float2 bC = *(const float2*)(bB + ro + c);
            const float2 bR = *(const float2*)(bB + ro + colR);
            const float2 dL = *(const float2*)(dB + ro + colL);
            const float2 dC = *(const float2*)(dB + ro + c);
            const float2 dR = *(const float2*)(dB + ro + colR);
            const float2 zL = *(const float2*)(zB + ro + colL);
            const float2 zC = *(const float2*)(zB + ro + c);
            const float2 zR = *(const float2*)(zB + ro + colR);

            // px0 (col c): taps c-2,c-1,[c],c+1,c+2
            const float iA = __builtin_amdgcn_rcpf(zC.x);
            const float w0 = wexp(zL.x, iA, kA0);
            const float w1 = wexp(zL.y, iA, kA1);
            const float w3 = wexp(zC.y, iA, kA3);
            const float w4 = wexp(zR.x, iA, kA4);
            const float wr = __builtin_amdgcn_rcpf(1.0f + w0 + w1 + w3 + w4);
            pb0[s] = fmaf(w0, bL.x, fmaf(w1, bL.y, fmaf(w3, bC.y, fmaf(w4, bR.x, bC.x)))) * wr;
            pd0[s] = fmaf(w0, dL.x, fmaf(w1, dL.y, fmaf(w3, dC.y, fmaf(w4, dR.x, dC.x)))) * wr;
            pz0[s] = zC.x;

            // px1 (col c+1): taps c-1,c,[c+1],c+2,c+3
            const float iB = __builtin_amdgcn_rcpf(zC.y);
            const float u0 = wexp(zL.y, iB, kB0);
            const float u1 = wexp(zC.x, iB, kB1);
            const float u3 = wexp(zR.x, iB, kB3);
            const float u4 = wexp(zR.y, iB, kB4);
            const float ur = __builtin_amdgcn_rcpf(1.0f + u0 + u1 + u3 + u4);
            pb1[s] = fmaf(u0, bL.y, fmaf(u1, bC.x, fmaf(u3, bR.x, fmaf(u4, bR.y, bC.y)))) * ur;
            pd1[s] = fmaf(u0, dL.y, fmaf(u1, dC.x, fmaf(u3, dR.x, fmaf(u4, dR.y, dC.y)))) * ur;
            pz1[s] = zC.y;
        } else {
            // zero-pad row: z=0 -> vertical tap weight underflows to exact 0
            pb0[s] = pb1[s] = pd0[s] = pd1[s] = 0.0f;
            pz0[s] = pz1[s] = 0.0f;
        }

        if (i >= 4) {
            const int orow = y0 + i - 4;           // output row (always valid)
            const int sm2 = (i - 4) % 5, sm1 = (i - 3) % 5, sc = (i - 2) % 5;
            const int sp1 = (i - 1) % 5, sp2 = i % 5;

            // vertical blur px0
            const float izA = __builtin_amdgcn_rcpf(pz0[sc]);
            const float v0 = wexp(pz0[sm2], izA, ks4);
            const float v1 = wexp(pz0[sm1], izA, ks1);
            const float v3 = wexp(pz0[sp1], izA, ks1);
            const float v4 = wexp(pz0[sp2], izA, ks4);
            const float vr = __builtin_amdgcn_rcpf(1.0f + v0 + v1 + v3 + v4);
            const float bmA = fmaf(v0, pb0[sm2], fmaf(v1, pb0[sm1], fmaf(v3, pb0[sp1], fmaf(v4, pb0[sp2], pb0[sc])))) * vr;
            const float dmA = fmaf(v0, pd0[sm2], fmaf(v1, pd0[sm1], fmaf(v3, pd0[sp1], fmaf(v4, pd0[sp2], pd0[sc])))) * vr;

            // vertical blur px1
            const float izB = __builtin_amdgcn_rcpf(pz1[sc]);
            const float x0 = wexp(pz1[sm2], izB, ks4);
            const float x1 = wexp(pz1[sm1], izB, ks1);
            const float x3 = wexp(pz1[sp1], izB, ks1);
            const float x4 = wexp(pz1[sp2], izB, ks4);
            const float xr = __builtin_amdgcn_rcpf(1.0f + x0 + x1 + x3 + x4);
            const float bmB = fmaf(x0, pb1[sm2], fmaf(x1, pb1[sm1], fmaf(x3, pb1[sp1], fmaf(x4, pb1[sp2], pb1[sc])))) * xr;
            const float dmB = fmaf(x0, pd1[sm2], fmaf(x1, pd1[sm1], fmaf(x3, pd1[sp1], fmaf(x4, pd1[sp2], pd1[sc])))) * xr;

            // contrast blend (raw center re-read: L1-hot, loaded 2 iters ago)
            const size_t oo = (size_t)orow * W + c;
            const float2 bc = *(const float2*)(bB + oo);
            const float2 dc = *(const float2*)(dB + oo);

            const float devbA = exp2f(de * __log2f(fmaxf(fabsf(bc.x - bmA), 1e-8f))) * ce;
            const float devdA = fmaxf(exp2f(de * __log2f(fmaxf(fabsf(dc.x - dmA), 1e-8f))), dke);
            const float wA = __builtin_amdgcn_rcpf(devbA + devdA);
            const float resA = fmaf(devdA, bc.x, devbA * dc.x) * wA;

            const float devbB = exp2f(de * __log2f(fmaxf(fabsf(bc.y - bmB), 1e-8f))) * ce;
            const float devdB = fmaxf(exp2f(de * __log2f(fmaxf(fabsf(dc.y - dmB), 1e-8f))), dke);
            const float wB = __builtin_amdgcn_rcpf(devbB + devdB);
            const float resB = fmaf(devdB, bc.y, devbB * dc.y) * wB;

            *(float2*)(outB + oo) = make_float2(resA, resB);
        }
    }
}

extern "C" void kernel_launch(void* const* d_in, const int* in_sizes, int n_in,
                              void* d_out, int out_size, void* d_ws, size_t ws_size,
                              hipStream_t stream)
{
    const float* bright = (const float*)d_in[0];
    const float* dark   = (const float*)d_in[1];
    const float* depths = (const float*)d_in[2];
    const float* p_dv   = (const float*)d_in[3];
    const float* p_sv   = (const float*)d_in[4];
    const float* p_de   = (const float*)d_in[5];
    const float* p_deps = (const float*)d_in[6];
    const float* p_ce   = (const float*)d_in[7];
    float* out = (float*)d_out;

    const int H = 1024, W = 1024;
    const int B = in_sizes[0] / (H * W);

    dim3 grid(W / XCOLS, H / TH, B);
    dim3 block(256);
    bilateral_fused<<<grid, block, 0, stream>>>(bright, dark, depths,
                                                p_dv, p_sv, p_de, p_deps, p_ce,
                                                out, H, W);
}

// Round 6
// 161.456 us; speedup vs baseline: 1.1037x; 1.1037x over previous
//
#include <hip/hip_runtime.h>

#define TH 16
#define W_ 1024
#define H_ 1024

__device__ __forceinline__ float wexp1(float zp, float iz, float kd, float kspat) {
    const float u = fmaf(zp, iz, -1.0f);
    return __builtin_amdgcn_exp2f(fmaf(u * kd, u, kspat));
}

// 5-tap depth-guided blur of (b,d) around center; taps m2,m1,[c],p1,p2
__device__ __forceinline__ void blur5(
    float zm2, float zm1, float zc, float zp1, float zp2,
    float bm2, float bm1, float bc, float bp1, float bp2,
    float dm2, float dm1, float dc, float dp1, float dp2,
    float kd, float ks1, float ks4,
    float& ob, float& od)
{
    const float iz = __builtin_amdgcn_rcpf(zc);
    const float w0 = wexp1(zm2, iz, kd, ks4);
    const float w1 = wexp1(zm1, iz, kd, ks1);
    const float w3 = wexp1(zp1, iz, kd, ks1);
    const float w4 = wexp1(zp2, iz, kd, ks4);
    const float wr = __builtin_amdgcn_rcpf(1.0f + w0 + w1 + w3 + w4);
    ob = fmaf(w0, bm2, fmaf(w1, bm1, fmaf(w3, bp1, fmaf(w4, bp2, bc)))) * wr;
    od = fmaf(w0, dm2, fmaf(w1, dm1, fmaf(w3, dp1, fmaf(w4, dp2, dc)))) * wr;
}

__device__ __forceinline__ float blend1(float bc, float dc, float bm, float dm,
                                        float de, float dke, float ce) {
    const float devb = __builtin_amdgcn_exp2f(
        de * __builtin_amdgcn_logf(fmaxf(fabsf(bc - bm), 1e-8f))) * ce;
    const float devd = fmaxf(__builtin_amdgcn_exp2f(
        de * __builtin_amdgcn_logf(fmaxf(fabsf(dc - dm), 1e-8f))), dke);
    const float wr = __builtin_amdgcn_rcpf(devb + devd);
    return fmaf(devd, bc, devb * dc) * wr;
}

// horizontal blur of row gy into pipeline slot (sb,sd,sz); 4 px at cols c..c+3
__device__ __forceinline__ void stage_row(
    int gy, const float* __restrict__ bB, const float* __restrict__ dB,
    const float* __restrict__ zB,
    int c, int colL2, int colR2, bool eL, bool eR,
    float kd, float ks1, float ks4,
    float4& sb, float4& sd, float4& sz)
{
    if ((unsigned)gy < (unsigned)H_) {   // block-uniform
        const size_t ro = (size_t)gy * W_;
        const float2 lb = *(const float2*)(bB + ro + colL2);
        const float4 cb = *(const float4*)(bB + ro + c);
        const float2 rb = *(const float2*)(bB + ro + colR2);
        const float2 ld = *(const float2*)(dB + ro + colL2);
        const float4 cd = *(const float4*)(dB + ro + c);
        const float2 rd = *(const float2*)(dB + ro + colR2);
        float2 lz = *(const float2*)(zB + ro + colL2);
        const float4 cz = *(const float4*)(zB + ro + c);
        float2 rz = *(const float2*)(zB + ro + colR2);
        // image-edge taps: poison depth -> t huge -> t*kd*t = -inf -> w = 0
        // (matches the reference's zero-padding exactly)
        if (eL) { lz.x = 1e18f; lz.y = 1e18f; }
        if (eR) { rz.x = 1e18f; rz.y = 1e18f; }
        // window cols: lz(c-2,c-1) cz(c..c+3) rz(c+4,c+5)
        blur5(lz.x, lz.y, cz.x, cz.y, cz.z,  lb.x, lb.y, cb.x, cb.y, cb.z,
              ld.x, ld.y, cd.x, cd.y, cd.z,  kd, ks1, ks4, sb.x, sd.x);
        blur5(lz.y, cz.x, cz.y, cz.z, cz.w,  lb.y, cb.x, cb.y, cb.z, cb.w,
              ld.y, cd.x, cd.y, cd.z, cd.w,  kd, ks1, ks4, sb.y, sd.y);
        blur5(cz.x, cz.y, cz.z, cz.w, rz.x,  cb.x, cb.y, cb.z, cb.w, rb.x,
              cd.x, cd.y, cd.z, cd.w, rd.x,  kd, ks1, ks4, sb.z, sd.z);
        blur5(cz.y, cz.z, cz.w, rz.x, rz.y,  cb.y, cb.z, cb.w, rb.x, rb.y,
              cd.y, cd.z, cd.w, rd.x, rd.y,  kd, ks1, ks4, sb.w, sd.w);
        sz = cz;
    } else {
        // zero-pad row: z=0 -> vertical tap t=-1 -> w = exp2(kd+ks) = 0 exact
        sb = make_float4(0.f, 0.f, 0.f, 0.f);
        sd = make_float4(0.f, 0.f, 0.f, 0.f);
        sz = make_float4(0.f, 0.f, 0.f, 0.f);
    }
}

// stage row (y0+i-2) into slot S, then vertical blur + blend of row (y0+i-4)
#define STEP(S, S0, S1, S2, S3, S4, I)                                        \
  {                                                                           \
    stage_row(y0 + (I) - 2, bB, dB, zB, c, colL2, colR2, eL, eR,              \
              kd, ks1, ks4, pb[S], pd[S], pz[S]);                             \
    float4 bm, dm;                                                            \
    blur5(pz[S0].x, pz[S1].x, pz[S2].x, pz[S3].x, pz[S4].x,                   \
          pb[S0].x, pb[S1].x, pb[S2].x, pb[S3].x, pb[S4].x,                   \
          pd[S0].x, pd[S1].x, pd[S2].x, pd[S3].x, pd[S4].x,                   \
          kd, ks1, ks4, bm.x, dm.x);                                          \
    blur5(pz[S0].y, pz[S1].y, pz[S2].y, pz[S3].y, pz[S4].y,                   \
          pb[S0].y, pb[S1].y, pb[S2].y, pb[S3].y, pb[S4].y,                   \
          pd[S0].y, pd[S1].y, pd[S2].y, pd[S3].y, pd[S4].y,                   \
          kd, ks1, ks4, bm.y, dm.y);                                          \
    blur5(pz[S0].z, pz[S1].z, pz[S2].z, pz[S3].z, pz[S4].z,                   \
          pb[S0].z, pb[S1].z, pb[S2].z, pb[S3].z, pb[S4].z,                   \
          pd[S0].z, pd[S1].z, pd[S2].z, pd[S3].z, pd[S4].z,                   \
          kd, ks1, ks4, bm.z, dm.z);                                          \
    blur5(pz[S0].w, pz[S1].w, pz[S2].w, pz[S3].w, pz[S4].w,                   \
          pb[S0].w, pb[S1].w, pb[S2].w, pb[S3].w, pb[S4].w,                   \
          pd[S0].w, pd[S1].w, pd[S2].w, pd[S3].w, pd[S4].w,                   \
          kd, ks1, ks4, bm.w, dm.w);                                          \
    const size_t oo = (size_t)(y0 + (I) - 4) * W_ + c;                        \
    const float4 rb4 = *(const float4*)(bB + oo);                             \
    const float4 rd4 = *(const float4*)(dB + oo);                             \
    float4 res;                                                               \
    res.x = blend1(rb4.x, rd4.x, bm.x, dm.x, de, dke, ce);                    \
    res.y = blend1(rb4.y, rd4.y, bm.y, dm.y, de, dke, ce);                    \
    res.z = blend1(rb4.z, rd4.z, bm.z, dm.z, de, dke, ce);                    \
    res.w = blend1(rb4.w, rd4.w, bm.w, dm.w, de, dke, ce);                    \
    *(float4*)(outB + oo) = res;                                              \
  }

__global__ __launch_bounds__(256, 2)
void bilateral_fused(const float* __restrict__ bright,
                     const float* __restrict__ dark,
                     const float* __restrict__ depths,
                     const float* __restrict__ p_dv,
                     const float* __restrict__ p_sv,
                     const float* __restrict__ p_de,
                     const float* __restrict__ p_deps,
                     const float* __restrict__ p_ce,
                     float* __restrict__ out)
{
    const float LOG2E = 1.44269504088896340736f;
    const float kd  = -LOG2E / (2.0f * p_dv[0]);   // ~ -1803
    const float ks  = -LOG2E / (2.0f * p_sv[0]);
    const float de  = p_de[0];
    const float dke = p_deps[0];
    const float ce  = p_ce[0];
    const float ks1 = ks;
    const float ks4 = 4.0f * ks;

    const int t  = threadIdx.x;           // 0..255
    const int c  = 4 * t;                 // cols c..c+3
    const int y0 = blockIdx.y * TH;

    const size_t plane = (size_t)H_ * W_;
    const float* bB = bright + (size_t)blockIdx.z * plane;
    const float* dB = dark   + (size_t)blockIdx.z * plane;
    const float* zB = depths + (size_t)blockIdx.z * plane;
    float*     outB = out    + (size_t)blockIdx.z * plane;

    const int  colL2 = max(c - 2, 0);        // float2 [c-2,c-1], 8B aligned
    const int  colR2 = min(c + 4, W_ - 2);   // float2 [c+4,c+5]
    const bool eL = (c == 0);
    const bool eR = (c + 4 >= W_);

    // 5-deep register pipeline: horizontally-blurred (b,d) + center depths
    float4 pb[5], pd[5], pz[5];

    // warm-up: steps i = 0..3 -> slots 0..3 (no output yet)
    stage_row(y0 - 2, bB, dB, zB, c, colL2, colR2, eL, eR, kd, ks1, ks4, pb[0], pd[0], pz[0]);
    stage_row(y0 - 1, bB, dB, zB, c, colL2, colR2, eL, eR, kd, ks1, ks4, pb[1], pd[1], pz[1]);
    stage_row(y0 + 0, bB, dB, zB, c, colL2, colR2, eL, eR, kd, ks1, ks4, pb[2], pd[2], pz[2]);
    stage_row(y0 + 1, bB, dB, zB, c, colL2, colR2, eL, eR, kd, ks1, ks4, pb[3], pd[3], pz[3]);

    // steady state: steps i = 4..18 as 3 rolled iterations of 5 (static slots)
    int i = 4;
#pragma unroll 1
    for (int it = 0; it < 3; ++it) {
        STEP(4, 0, 1, 2, 3, 4, i + 0)
        STEP(0, 1, 2, 3, 4, 0, i + 1)
        STEP(1, 2, 3, 4, 0, 1, i + 2)
        STEP(2, 3, 4, 0, 1, 2, i + 3)
        STEP(3, 4, 0, 1, 2, 3, i + 4)
        i += 5;
    }
    // final step i = 19 -> output row y0+15
    STEP(4, 0, 1, 2, 3, 4, 19)
}

extern "C" void kernel_launch(void* const* d_in, const int* in_sizes, int n_in,
                              void* d_out, int out_size, void* d_ws, size_t ws_size,
                              hipStream_t stream)
{
    const float* bright = (const float*)d_in[0];
    const float* dark   = (const float*)d_in[1];
    const float* depths = (const float*)d_in[2];
    const float* p_dv   = (const float*)d_in[3];
    const float* p_sv   = (const float*)d_in[4];
    const float* p_de   = (const float*)d_in[5];
    const float* p_deps = (const float*)d_in[6];
    const float* p_ce   = (const float*)d_in[7];
    float* out = (float*)d_out;

    const int B = in_sizes[0] / (H_ * W_);

    dim3 grid(1, H_ / TH, B);
    dim3 block(256);
    bilateral_fused<<<grid, block, 0, stream>>>(bright, dark, depths,
                                                p_dv, p_sv, p_de, p_deps, p_ce,
                                                out);
}

// Round 7
// 156.444 us; speedup vs baseline: 1.1390x; 1.0320x over previous
//
#include <hip/hip_runtime.h>

#define TH 8
#define W_ 1024
#define H_ 1024

__device__ __forceinline__ float wexp1(float zp, float iz, float kd, float kspat) {
    const float u = fmaf(zp, iz, -1.0f);
    return __builtin_amdgcn_exp2f(fmaf(u * kd, u, kspat));
}

// 5-tap depth-guided blur of (b,d) around center; taps m2,m1,[c],p1,p2
__device__ __forceinline__ void blur5(
    float zm2, float zm1, float zc, float zp1, float zp2,
    float bm2, float bm1, float bc, float bp1, float bp2,
    float dm2, float dm1, float dc, float dp1, float dp2,
    float kd, float ks1, float ks4,
    float& ob, float& od)
{
    const float iz = __builtin_amdgcn_rcpf(zc);
    const float w0 = wexp1(zm2, iz, kd, ks4);
    const float w1 = wexp1(zm1, iz, kd, ks1);
    const float w3 = wexp1(zp1, iz, kd, ks1);
    const float w4 = wexp1(zp2, iz, kd, ks4);
    const float wr = __builtin_amdgcn_rcpf(1.0f + w0 + w1 + w3 + w4);
    ob = fmaf(w0, bm2, fmaf(w1, bm1, fmaf(w3, bp1, fmaf(w4, bp2, bc)))) * wr;
    od = fmaf(w0, dm2, fmaf(w1, dm1, fmaf(w3, dp1, fmaf(w4, dp2, dc)))) * wr;
}

__device__ __forceinline__ float blend1(float bc, float dc, float bm, float dm,
                                        float de, float dke, float ce) {
    const float devb = __builtin_amdgcn_exp2f(
        de * __builtin_amdgcn_logf(fmaxf(fabsf(bc - bm), 1e-8f))) * ce;
    const float devd = fmaxf(__builtin_amdgcn_exp2f(
        de * __builtin_amdgcn_logf(fmaxf(fabsf(dc - dm), 1e-8f))), dke);
    const float wr = __builtin_amdgcn_rcpf(devb + devd);
    return fmaf(devd, bc, devb * dc) * wr;
}

// horizontal blur of row gy into pipeline slot (sb,sd,sz); 4 px at cols c..c+3
__device__ __forceinline__ void stage_row(
    int gy, const float* __restrict__ bB, const float* __restrict__ dB,
    const float* __restrict__ zB,
    int c, int colL2, int colR2, bool eL, bool eR,
    float kd, float ks1, float ks4,
    float4& sb, float4& sd, float4& sz)
{
    if ((unsigned)gy < (unsigned)H_) {   // block-uniform
        const size_t ro = (size_t)gy * W_;
        const float2 lb = *(const float2*)(bB + ro + colL2);
        const float4 cb = *(const float4*)(bB + ro + c);
        const float2 rb = *(const float2*)(bB + ro + colR2);
        const float2 ld = *(const float2*)(dB + ro + colL2);
        const float4 cd = *(const float4*)(dB + ro + c);
        const float2 rd = *(const float2*)(dB + ro + colR2);
        float2 lz = *(const float2*)(zB + ro + colL2);
        const float4 cz = *(const float4*)(zB + ro + c);
        float2 rz = *(const float2*)(zB + ro + colR2);
        // image-edge taps: poison depth -> |t| huge -> kd*t^2 = -inf -> w = 0
        // (matches the reference's zero-padding exactly)
        if (eL) { lz.x = 1e18f; lz.y = 1e18f; }
        if (eR) { rz.x = 1e18f; rz.y = 1e18f; }
        // window cols: lz(c-2,c-1) cz(c..c+3) rz(c+4,c+5)
        blur5(lz.x, lz.y, cz.x, cz.y, cz.z,  lb.x, lb.y, cb.x, cb.y, cb.z,
              ld.x, ld.y, cd.x, cd.y, cd.z,  kd, ks1, ks4, sb.x, sd.x);
        blur5(lz.y, cz.x, cz.y, cz.z, cz.w,  lb.y, cb.x, cb.y, cb.z, cb.w,
              ld.y, cd.x, cd.y, cd.z, cd.w,  kd, ks1, ks4, sb.y, sd.y);
        blur5(cz.x, cz.y, cz.z, cz.w, rz.x,  cb.x, cb.y, cb.z, cb.w, rb.x,
              cd.x, cd.y, cd.z, cd.w, rd.x,  kd, ks1, ks4, sb.z, sd.z);
        blur5(cz.y, cz.z, cz.w, rz.x, rz.y,  cb.y, cb.z, cb.w, rb.x, rb.y,
              cd.y, cd.z, cd.w, rd.x, rd.y,  kd, ks1, ks4, sb.w, sd.w);
        sz = cz;
    } else {
        // zero-pad row: z=0 -> vertical tap t=-1 -> w = exp2(kd+ks) = 0 exact
        sb = make_float4(0.f, 0.f, 0.f, 0.f);
        sd = make_float4(0.f, 0.f, 0.f, 0.f);
        sz = make_float4(0.f, 0.f, 0.f, 0.f);
    }
}

// stage row (y0+i-2) into slot S, then vertical blur + blend of row (y0+i-4)
#define STEP(S, S0, S1, S2, S3, S4, I)                                        \
  {                                                                           \
    stage_row(y0 + (I) - 2, bB, dB, zB, c, colL2, colR2, eL, eR,              \
              kd, ks1, ks4, pb[S], pd[S], pz[S]);                             \
    float4 bm, dm;                                                            \
    blur5(pz[S0].x, pz[S1].x, pz[S2].x, pz[S3].x, pz[S4].x,                   \
          pb[S0].x, pb[S1].x, pb[S2].x, pb[S3].x, pb[S4].x,                   \
          pd[S0].x, pd[S1].x, pd[S2].x, pd[S3].x, pd[S4].x,                   \
          kd, ks1, ks4, bm.x, dm.x);                                          \
    blur5(pz[S0].y, pz[S1].y, pz[S2].y, pz[S3].y, pz[S4].y,                   \
          pb[S0].y, pb[S1].y, pb[S2].y, pb[S3].y, pb[S4].y,                   \
          pd[S0].y, pd[S1].y, pd[S2].y, pd[S3].y, pd[S4].y,                   \
          kd, ks1, ks4, bm.y, dm.y);                                          \
    blur5(pz[S0].z, pz[S1].z, pz[S2].z, pz[S3].z, pz[S4].z,                   \
          pb[S0].z, pb[S1].z, pb[S2].z, pb[S3].z, pb[S4].z,                   \
          pd[S0].z, pd[S1].z, pd[S2].z, pd[S3].z, pd[S4].z,                   \
          kd, ks1, ks4, bm.z, dm.z);                                          \
    blur5(pz[S0].w, pz[S1].w, pz[S2].w, pz[S3].w, pz[S4].w,                   \
          pb[S0].w, pb[S1].w, pb[S2].w, pb[S3].w, pb[S4].w,                   \
          pd[S0].w, pd[S1].w, pd[S2].w, pd[S3].w, pd[S4].w,                   \
          kd, ks1, ks4, bm.w, dm.w);                                          \
    const size_t oo = (size_t)(y0 + (I) - 4) * W_ + c;                        \
    const float4 rb4 = *(const float4*)(bB + oo);                             \
    const float4 rd4 = *(const float4*)(dB + oo);                             \
    float4 res;                                                               \
    res.x = blend1(rb4.x, rd4.x, bm.x, dm.x, de, dke, ce);                    \
    res.y = blend1(rb4.y, rd4.y, bm.y, dm.y, de, dke, ce);                    \
    res.z = blend1(rb4.z, rd4.z, bm.z, dm.z, de, dke, ce);                    \
    res.w = blend1(rb4.w, rd4.w, bm.w, dm.w, de, dke, ce);                    \
    *(float4*)(outB + oo) = res;                                              \
  }

__global__ __launch_bounds__(256, 4)
void bilateral_fused(const float* __restrict__ bright,
                     const float* __restrict__ dark,
                     const float* __restrict__ depths,
                     const float* __restrict__ p_dv,
                     const float* __restrict__ p_sv,
                     const float* __restrict__ p_de,
                     const float* __restrict__ p_deps,
                     const float* __restrict__ p_ce,
                     float* __restrict__ out)
{
    const float LOG2E = 1.44269504088896340736f;
    const float kd  = -LOG2E / (2.0f * p_dv[0]);   // ~ -1803
    const float ks  = -LOG2E / (2.0f * p_sv[0]);
    const float de  = p_de[0];
    const float dke = p_deps[0];
    const float ce  = p_ce[0];
    const float ks1 = ks;
    const float ks4 = 4.0f * ks;

    const int t  = threadIdx.x;           // 0..255
    const int c  = 4 * t;                 // cols c..c+3
    const int y0 = blockIdx.y * TH;

    const size_t plane = (size_t)H_ * W_;
    const float* bB = bright + (size_t)blockIdx.z * plane;
    const float* dB = dark   + (size_t)blockIdx.z * plane;
    const float* zB = depths + (size_t)blockIdx.z * plane;
    float*     outB = out    + (size_t)blockIdx.z * plane;

    const int  colL2 = max(c - 2, 0);        // float2 [c-2,c-1], 8B aligned
    const int  colR2 = min(c + 4, W_ - 2);   // float2 [c+4,c+5]
    const bool eL = (c == 0);
    const bool eR = (c + 4 >= W_);

    // 5-deep register pipeline: horizontally-blurred (b,d) + center depths
    float4 pb[5], pd[5], pz[5];

    // warm-up: steps i = 0..3 -> slots 0..3 (no output yet)
    stage_row(y0 - 2, bB, dB, zB, c, colL2, colR2, eL, eR, kd, ks1, ks4, pb[0], pd[0], pz[0]);
    stage_row(y0 - 1, bB, dB, zB, c, colL2, colR2, eL, eR, kd, ks1, ks4, pb[1], pd[1], pz[1]);
    stage_row(y0 + 0, bB, dB, zB, c, colL2, colR2, eL, eR, kd, ks1, ks4, pb[2], pd[2], pz[2]);
    stage_row(y0 + 1, bB, dB, zB, c, colL2, colR2, eL, eR, kd, ks1, ks4, pb[3], pd[3], pz[3]);

    // steady state: steps i = 4..11, fully static slot rotation (TH = 8)
    STEP(4, 0, 1, 2, 3, 4,  4)
    STEP(0, 1, 2, 3, 4, 0,  5)
    STEP(1, 2, 3, 4, 0, 1,  6)
    STEP(2, 3, 4, 0, 1, 2,  7)
    STEP(3, 4, 0, 1, 2, 3,  8)
    STEP(4, 0, 1, 2, 3, 4,  9)
    STEP(0, 1, 2, 3, 4, 0, 10)
    STEP(1, 2, 3, 4, 0, 1, 11)
}

extern "C" void kernel_launch(void* const* d_in, const int* in_sizes, int n_in,
                              void* d_out, int out_size, void* d_ws, size_t ws_size,
                              hipStream_t stream)
{
    const float* bright = (const float*)d_in[0];
    const float* dark   = (const float*)d_in[1];
    const float* depths = (const float*)d_in[2];
    const float* p_dv   = (const float*)d_in[3];
    const float* p_sv   = (const float*)d_in[4];
    const float* p_de   = (const float*)d_in[5];
    const float* p_deps = (const float*)d_in[6];
    const float* p_ce   = (const float*)d_in[7];
    float* out = (float*)d_out;

    const int B = in_sizes[0] / (H_ * W_);

    dim3 grid(1, H_ / TH, B);
    dim3 block(256);
    bilateral_fused<<<grid, block, 0, stream>>>(bright, dark, depths,
                                                p_dv, p_sv, p_de, p_deps, p_ce,
                                                out);
}